// Round 10
// baseline (264.301 us; speedup 1.0000x reference)
//
#include <hip/hip_runtime.h>
#include <math.h>

#define IN_C  256
#define HID_C 128
#define OUT_C 64

typedef short bf16x8 __attribute__((ext_vector_type(8)));   // 8 bf16 = 4 VGPR
typedef float f32x4  __attribute__((ext_vector_type(4)));   // MFMA acc

// ---------------- bf16 helpers (bit ops; RNE pack) ----------------
__device__ __forceinline__ unsigned short f2bf(float f) {
    unsigned u = __float_as_uint(f);
    unsigned rounding = 0x7FFFu + ((u >> 16) & 1u);
    return (unsigned short)((u + rounding) >> 16);
}

// ---------------- edge dtype detection ----------------
__global__ void detect_kernel(const void* edges, int E, int n_nodes, int* flag) {
    if (threadIdx.x == 0 && blockIdx.x == 0) {
        const long long* p = (const long long*)edges;
        int k = E < 64 ? E : 64;
        int is64 = 1;
        for (int i = 0; i < k; ++i) {
            long long v = p[i];
            if (v < 0 || v >= n_nodes) { is64 = 0; break; }
        }
        *flag = is64;
    }
}

__device__ __forceinline__ int load_edge(const void* edges, size_t idx, int is64) {
    return is64 ? (int)((const long long*)edges)[idx] : ((const int*)edges)[idx];
}

// ---------------- W -> Wt[col][k] bf16 (one-time, tiny) ----------------
__global__ void convert_wt(const float* __restrict__ W, unsigned short* __restrict__ Wt,
                           int K, int N) {
    int idx = blockIdx.x * 256 + threadIdx.x;
    if (idx >= K * N) return;
    int k = idx / N, n_ = idx % N;
    Wt[(size_t)n_ * K + k] = f2bf(W[idx]);
}

__global__ void zero8(int* counts8, int n8) {
    int i = blockIdx.x * 256 + threadIdx.x;
    if (i < n8) counts8[i] = 0;
}

// ---------------- FUSED: x->bf16 convert || XCD-replica degree count + rank ----------------
// Count branch: 4 edges/thread, PHASE-SEPARATED (4 loads in flight -> 4
// independent atomic chains in flight -> 4 rank stores). MLP probe vs r9's 1/thread.
// counts8 [xcc][d]: each 64B line owned by one XCD (replica). rank = local | xcc<<28.
__global__ __launch_bounds__(256) void conv_count(
    const float* __restrict__ x, unsigned short* __restrict__ xb, int nconv,
    const void* edges, const int* __restrict__ flag,
    int* counts8, int* __restrict__ rank, int E, int n, int CONV) {
    const int bid = blockIdx.x;
    if (bid < CONV) {
        int t = bid * 256 + threadIdx.x;
        int stride = CONV * 256;
        for (int i = t; i < nconv; i += stride) {
            const float4* p = (const float4*)(x + (size_t)i * 8);
            float4 a = p[0], b = p[1];
            union { unsigned short u[8]; uint4 v; } t8;
            t8.u[0] = f2bf(a.x); t8.u[1] = f2bf(a.y); t8.u[2] = f2bf(a.z); t8.u[3] = f2bf(a.w);
            t8.u[4] = f2bf(b.x); t8.u[5] = f2bf(b.y); t8.u[6] = f2bf(b.z); t8.u[7] = f2bf(b.w);
            *(uint4*)(xb + (size_t)i * 8) = t8.v;
        }
        return;
    }
    const int f = *flag;
    const int e0 = (bid - CONV) * 1024 + threadIdx.x;
    // hwreg(id=20 HW_REG_XCC_ID, offset=0, size=4): imm = ((4-1)<<11)|20
    unsigned xcc = (unsigned)__builtin_amdgcn_s_getreg((3 << 11) | 20) & 7u;
    int d[4]; bool v[4];
    #pragma unroll
    for (int k = 0; k < 4; ++k) {
        int e = e0 + k * 256;
        v[k] = (e < E);
        d[k] = v[k] ? load_edge(edges, (size_t)E + e, f) : 0;
    }
    int rl[4];
    #pragma unroll
    for (int k = 0; k < 4; ++k)
        if (v[k]) rl[k] = atomicAdd(&counts8[(size_t)xcc * n + d[k]], 1);
    #pragma unroll
    for (int k = 0; k < 4; ++k)
        if (v[k]) rank[e0 + k * 256] = rl[k] | (int)(xcc << 28);
}

// ---------------- scan over summed replicas + xoff + dis, block phase ----------------
__global__ void scan8_block_dis(const int* __restrict__ counts8, int* __restrict__ xoff,
                                int* __restrict__ deg, int* __restrict__ excl,
                                int* __restrict__ blockSums, float* __restrict__ dis, int n) {
    __shared__ int tmp[256];
    int i = blockIdx.x * 256 + threadIdx.x;
    int v = 0;
    if (i < n) {
        int s = 0;
        #pragma unroll
        for (int xg = 0; xg < 8; ++xg) {
            int c = counts8[(size_t)xg * n + i];
            xoff[(size_t)xg * n + i] = s;
            s += c;
        }
        v = s;
        deg[i] = s;
        dis[i] = rsqrtf((float)s + 1.0f);   // +1 self-loop
    }
    tmp[threadIdx.x] = v;
    __syncthreads();
    for (int off = 1; off < 256; off <<= 1) {
        int t = (threadIdx.x >= off) ? tmp[threadIdx.x - off] : 0;
        __syncthreads();
        if (threadIdx.x >= off) tmp[threadIdx.x] += t;
        __syncthreads();
    }
    if (i < n) excl[i] = tmp[threadIdx.x] - v;
    if (threadIdx.x == 255) blockSums[blockIdx.x] = tmp[255];
}

__global__ void scan_sums(int* blockSums, int nb) {  // nb <= 512
    __shared__ int tmp[512];
    int v = (threadIdx.x < nb) ? blockSums[threadIdx.x] : 0;
    tmp[threadIdx.x] = v;
    __syncthreads();
    for (int off = 1; off < 512; off <<= 1) {
        int t = (threadIdx.x >= off) ? tmp[threadIdx.x - off] : 0;
        __syncthreads();
        if (threadIdx.x >= off) tmp[threadIdx.x] += t;
        __syncthreads();
    }
    if (threadIdx.x < nb) blockSums[threadIdx.x] = tmp[threadIdx.x] - v;
}

__global__ void add_offsets(int* __restrict__ excl, const int* __restrict__ blockSums, int n) {
    int i = blockIdx.x * 256 + threadIdx.x;
    if (i < n) excl[i] += blockSums[blockIdx.x];
}

// ---------------- FUSED: gemm1 (MFMA) || CSR fill (atomic-free) ----------------
// gemm: TM=64, KC=64, 24KB LDS -> 6 blocks/CU -> fill blocks keep ~24 waves/CU
// (r4's fusion failure was the 33.8KB/4-block cap; doesn't apply here).
// Block map (G gemm, F fill): bid<2G: even->gemm bid/2, odd->fill bid>>1;
// bid>=2G -> fill bid-G.
// LDS: linear rows (128B), T2 XOR-swizzle col16 ^= row&7 (conflict-free both sides).
// Fragments (r8/r9 HW-verified): A row=lane&15, k=ksub*32+8*(lane>>4)+j;
// B col=lane&15 same k; C/D col=lane&15, row=4*(lane>>4)+reg.
template<int TN, int K>
__global__ __launch_bounds__(256) void fused_gemm_fill(
    const unsigned short* __restrict__ A, const unsigned short* __restrict__ Wt,
    const float* __restrict__ dis, unsigned short* __restrict__ C, int M, int G,
    const void* edges, const int* __restrict__ flag,
    const int* __restrict__ row_ptr, const int* __restrict__ xoff,
    const int* __restrict__ rank, int* __restrict__ ssrc, int E, int n) {
    constexpr int TM = 64, KC = 64, NCF = TN / 16;
    __shared__ __align__(16) unsigned short A_lds[TM * KC];
    __shared__ __align__(16) unsigned short B_lds[TN * KC];
    const int bid = blockIdx.x;
    const bool is_gemm = (bid < 2 * G) && ((bid & 1) == 0);

    if (!is_gemm) {
        const int fb = (bid < 2 * G) ? (bid >> 1) : (bid - G);
        const int f = *flag;
        const int e0 = fb * 1024 + threadIdx.x;
        int d[4], s[4], rk[4]; bool v[4];
        #pragma unroll
        for (int k = 0; k < 4; ++k) {
            int e = e0 + k * 256;
            v[k] = (e < E);
            if (v[k]) {
                d[k]  = load_edge(edges, (size_t)E + e, f);
                s[k]  = load_edge(edges, e, f);
                rk[k] = rank[e];
            }
        }
        #pragma unroll
        for (int k = 0; k < 4; ++k) {
            if (v[k]) {
                int pos = row_ptr[d[k]] + xoff[(size_t)(rk[k] >> 28) * n + d[k]]
                        + (rk[k] & 0x0FFFFFFF);
                ssrc[pos] = s[k];
            }
        }
        return;
    }

    const int g = bid >> 1;
    const int tid  = threadIdx.x;
    const int wave = tid >> 6;
    const int lane = tid & 63;
    const int q    = lane >> 4;
    const int cl   = lane & 15;
    const long long row0 = (long long)g * TM;

    f32x4 acc[NCF];
    const f32x4 fzero = {0.f, 0.f, 0.f, 0.f};
    #pragma unroll
    for (int cf = 0; cf < NCF; ++cf) acc[cf] = fzero;

    for (int k0 = 0; k0 < K; k0 += KC) {
        #pragma unroll
        for (int p = 0; p < 2; ++p) {
            int i = p * 256 + tid;
            int r = i >> 3, c = i & 7;
            uint4 v = *(const uint4*)(A + (row0 + r) * K + k0 + c * 8);
            *(uint4*)((char*)A_lds + r * 128 + ((c ^ (r & 7)) * 16)) = v;
        }
        #pragma unroll
        for (int p = 0; p < TN / 32; ++p) {
            int i = p * 256 + tid;
            int bc = i >> 3, c = i & 7;
            uint4 v = *(const uint4*)(Wt + (size_t)bc * K + k0 + c * 8);
            *(uint4*)((char*)B_lds + bc * 128 + ((c ^ (bc & 7)) * 16)) = v;
        }
        __syncthreads();
        #pragma unroll
        for (int ksub = 0; ksub < 2; ++ksub) {
            const int cidx = ksub * 4 + q;
            const int r = wave * 16 + cl;
            bf16x8 af = *(const bf16x8*)((const char*)A_lds + r * 128 + ((cidx ^ (r & 7)) * 16));
            #pragma unroll
            for (int cf = 0; cf < NCF; ++cf) {
                const int bc = cf * 16 + cl;
                bf16x8 bfr = *(const bf16x8*)((const char*)B_lds + bc * 128 + ((cidx ^ (bc & 7)) * 16));
                acc[cf] = __builtin_amdgcn_mfma_f32_16x16x32_bf16(af, bfr, acc[cf], 0, 0, 0);
            }
        }
        __syncthreads();
    }
    #pragma unroll
    for (int j = 0; j < 4; ++j) {
        long long row = row0 + wave * 16 + q * 4 + j;
        if (row >= M) continue;
        float d = dis[row];
        #pragma unroll
        for (int cf = 0; cf < NCF; ++cf)
            C[row * TN + cf * 16 + cl] = f2bf(acc[cf][j] * d);
    }
}

// ---------------- MFMA bf16 GEMM (standalone; layer 2) ----------------
template<int TN, int K>
__global__ __launch_bounds__(256) void gemm_mfma_bb(
    const unsigned short* __restrict__ A, const unsigned short* __restrict__ Wt,
    const float* __restrict__ dis, unsigned short* __restrict__ C, int M) {
    constexpr int TM = 64, KC = 64, NCF = TN / 16;
    __shared__ __align__(16) unsigned short A_lds[TM * KC];
    __shared__ __align__(16) unsigned short B_lds[TN * KC];
    const int tid  = threadIdx.x;
    const int wave = tid >> 6;
    const int lane = tid & 63;
    const int q    = lane >> 4;
    const int cl   = lane & 15;
    const long long row0 = (long long)blockIdx.x * TM;

    f32x4 acc[NCF];
    const f32x4 fzero = {0.f, 0.f, 0.f, 0.f};
    #pragma unroll
    for (int cf = 0; cf < NCF; ++cf) acc[cf] = fzero;

    for (int k0 = 0; k0 < K; k0 += KC) {
        #pragma unroll
        for (int p = 0; p < 2; ++p) {
            int i = p * 256 + tid;
            int r = i >> 3, c = i & 7;
            uint4 v = *(const uint4*)(A + (row0 + r) * K + k0 + c * 8);
            *(uint4*)((char*)A_lds + r * 128 + ((c ^ (r & 7)) * 16)) = v;
        }
        #pragma unroll
        for (int p = 0; p < TN / 32; ++p) {
            int i = p * 256 + tid;
            int bc = i >> 3, c = i & 7;
            uint4 v = *(const uint4*)(Wt + (size_t)bc * K + k0 + c * 8);
            *(uint4*)((char*)B_lds + bc * 128 + ((c ^ (bc & 7)) * 16)) = v;
        }
        __syncthreads();
        #pragma unroll
        for (int ksub = 0; ksub < 2; ++ksub) {
            const int cidx = ksub * 4 + q;
            const int r = wave * 16 + cl;
            bf16x8 af = *(const bf16x8*)((const char*)A_lds + r * 128 + ((cidx ^ (r & 7)) * 16));
            #pragma unroll
            for (int cf = 0; cf < NCF; ++cf) {
                const int bc = cf * 16 + cl;
                bf16x8 bfr = *(const bf16x8*)((const char*)B_lds + bc * 128 + ((cidx ^ (bc & 7)) * 16));
                acc[cf] = __builtin_amdgcn_mfma_f32_16x16x32_bf16(af, bfr, acc[cf], 0, 0, 0);
            }
        }
        __syncthreads();
    }
    #pragma unroll
    for (int j = 0; j < 4; ++j) {
        long long row = row0 + wave * 16 + q * 4 + j;
        if (row >= M) continue;
        float d = dis[row];
        #pragma unroll
        for (int cf = 0; cf < NCF; ++cf)
            C[row * TN + cf * 16 + cl] = f2bf(acc[cf][j] * d);
    }
}

// ---------------- CSR gather on bf16 hs; output f32 or bf16; 8-deep MLP ----------------
template<int C, int NPB, bool OBF>
__global__ __launch_bounds__(256) void gather_layer_bf(
    const unsigned short* __restrict__ hs, const int* __restrict__ row_ptr,
    const int* __restrict__ deg, const int* __restrict__ ssrc,
    const float* __restrict__ dis, const float* __restrict__ bias,
    void* __restrict__ outp, int n) {
    constexpr int TPN = C / 8;
    const int local = threadIdx.x / TPN;
    const int lane  = threadIdx.x % TPN;
    const int i = blockIdx.x * NPB + local;
    if (i >= n) return;
    const uint4* h4 = (const uint4*)hs;
    float di = dis[i];
    float acc[8] = {};
    auto accum = [&](uint4 u) {
        acc[0] += __uint_as_float(u.x << 16);
        acc[1] += __uint_as_float(u.x & 0xffff0000u);
        acc[2] += __uint_as_float(u.y << 16);
        acc[3] += __uint_as_float(u.y & 0xffff0000u);
        acc[4] += __uint_as_float(u.z << 16);
        acc[5] += __uint_as_float(u.z & 0xffff0000u);
        acc[6] += __uint_as_float(u.w << 16);
        acc[7] += __uint_as_float(u.w & 0xffff0000u);
    };
    accum(h4[(size_t)i * TPN + lane]);     // self term
    const int start = row_ptr[i];
    const int cnt   = deg[i];
    const int* sp = ssrc + start;
    int j = 0;
    for (; j + 8 <= cnt; j += 8) {
        uint4 v[8];
        #pragma unroll
        for (int k = 0; k < 8; ++k) v[k] = h4[(size_t)sp[j + k] * TPN + lane];
        #pragma unroll
        for (int k = 0; k < 8; ++k) accum(v[k]);
    }
    for (; j + 4 <= cnt; j += 4) {
        uint4 v[4];
        #pragma unroll
        for (int k = 0; k < 4; ++k) v[k] = h4[(size_t)sp[j + k] * TPN + lane];
        #pragma unroll
        for (int k = 0; k < 4; ++k) accum(v[k]);
    }
    for (; j < cnt; ++j) accum(h4[(size_t)sp[j] * TPN + lane]);
    const float* bp = bias + lane * 8;
    float o[8];
    #pragma unroll
    for (int k = 0; k < 8; ++k) o[k] = bp[k] + di * acc[k];
    if constexpr (OBF) {
        union { unsigned short u[8]; uint4 v; } t8;
        #pragma unroll
        for (int k = 0; k < 8; ++k) t8.u[k] = f2bf(o[k]);
        *(uint4*)((unsigned short*)outp + (size_t)i * C + lane * 8) = t8.v;
    } else {
        float* op = (float*)outp + (size_t)i * C + lane * 8;
        *(float4*)op = make_float4(o[0], o[1], o[2], o[3]);
        *(float4*)(op + 4) = make_float4(o[4], o[5], o[6], o[7]);
    }
}

extern "C" void kernel_launch(void* const* d_in, const int* in_sizes, int n_in,
                              void* d_out, int out_size, void* d_ws, size_t ws_size,
                              hipStream_t stream) {
    const float* x     = (const float*)d_in[0];
    const void*  edges = d_in[1];
    const float* W1    = (const float*)d_in[2];
    const float* b1    = (const float*)d_in[3];
    const float* W2    = (const float*)d_in[4];
    const float* b2    = (const float*)d_in[5];
    float* out = (float*)d_out;

    const int n = in_sizes[0] / IN_C;      // 100000
    const int E = in_sizes[1] / 2;         // 1600000
    const int nb = (n + 255) / 256;        // 391

    // ---- workspace carve-up (256B-aligned), ~123 MB ----
    char* ws = (char*)d_ws;
    size_t off = 0;
    auto alloc = [&](size_t bytes) { char* p = ws + off; off += (bytes + 255) & ~(size_t)255; return p; };
    int*   flag      = (int*)  alloc(4);
    int*   counts8   = (int*)  alloc((size_t)n * 8 * 4);
    int*   xoff      = (int*)  alloc((size_t)n * 8 * 4);
    int*   deg       = (int*)  alloc((size_t)n * 4);
    int*   row_ptr   = (int*)  alloc((size_t)n * 4);
    int*   blockSums = (int*)  alloc(512 * 4);
    float* dis       = (float*)alloc((size_t)n * 4);
    int*   rank      = (int*)  alloc((size_t)E * 4);
    int*   ssrc      = (int*)  alloc((size_t)E * 4);
    unsigned short* xb   = (unsigned short*)alloc((size_t)(n + 64) * IN_C * 2);   // bf16 x (+tail pad)
    unsigned short* hs   = (unsigned short*)alloc((size_t)(n + 64) * HID_C * 2);  // layer1 hs; reused as hs2
    unsigned short* aggb = (unsigned short*)alloc((size_t)(n + 64) * HID_C * 2);  // bf16 layer-1 output
    unsigned short* Wt1  = (unsigned short*)alloc((size_t)IN_C * HID_C * 2);
    unsigned short* Wt2  = (unsigned short*)alloc((size_t)HID_C * OUT_C * 2);

    // 1. detect + weight transpose/convert + zero replica counters
    detect_kernel<<<1, 64, 0, stream>>>(edges, E, n, flag);
    convert_wt<<<(IN_C * HID_C + 255) / 256, 256, 0, stream>>>(W1, Wt1, IN_C, HID_C);
    convert_wt<<<(HID_C * OUT_C + 255) / 256, 256, 0, stream>>>(W2, Wt2, HID_C, OUT_C);
    zero8<<<(n * 8 + 255) / 256, 256, 0, stream>>>(counts8, n * 8);

    // 2. FUSED: x->bf16 || replica count+rank (4 edges/thread, phase-separated MLP)
    const int CONV = 512;
    const int nconv = n * IN_C / 8;
    conv_count<<<CONV + (E + 1023) / 1024, 256, 0, stream>>>(
        x, xb, nconv, edges, flag, counts8, rank, E, n, CONV);

    // 3. scan (+xoff, +deg, +dis) -> row_ptr
    scan8_block_dis<<<nb, 256, 0, stream>>>(counts8, xoff, deg, row_ptr, blockSums, dis, n);
    scan_sums<<<1, 512, 0, stream>>>(blockSums, nb);
    add_offsets<<<nb, 256, 0, stream>>>(row_ptr, blockSums, n);

    // 4. FUSED: layer-1 GEMM (hs = bf16((xb@W1)*dis)) || CSR fill
    const int G = (n + 63) / 64;           // 1563 gemm blocks
    const int F = (E + 1023) / 1024;       // 1563 fill blocks
    fused_gemm_fill<HID_C, IN_C><<<G + F, 256, 0, stream>>>(
        xb, Wt1, dis, hs, n, G, edges, flag, row_ptr, xoff, rank, ssrc, E, n);

    // 5. layer 1 aggregate: aggb = bf16(b1 + dis*(self+gather))
    gather_layer_bf<HID_C, 16, true><<<(n + 15) / 16, 256, 0, stream>>>(hs, row_ptr, deg, ssrc, dis, b1, aggb, n);

    // 6. layer 2: hs2 = bf16((aggb@W2)*dis); out = b2 + dis*(self+gather)
    gemm_mfma_bb<OUT_C, HID_C><<<(n + 63) / 64, 256, 0, stream>>>(aggb, Wt2, dis, hs, n);
    gather_layer_bf<OUT_C, 32, false><<<(n + 31) / 32, 256, 0, stream>>>(hs, row_ptr, deg, ssrc, dis, b2, out, n);
}

// Round 11
// 199.065 us; speedup vs baseline: 1.3277x; 1.3277x over previous
//
#include <hip/hip_runtime.h>
#include <math.h>

#define IN_C  256
#define HID_C 128
#define OUT_C 64
#define CHUNK 4096          // edges per partition chunk
#define MAXNB 400           // buckets (n/256) upper bound for LDS arrays

typedef short bf16x8 __attribute__((ext_vector_type(8)));   // 8 bf16 = 4 VGPR
typedef float f32x4  __attribute__((ext_vector_type(4)));   // MFMA acc

// ---------------- bf16 helpers (bit ops; RNE pack) ----------------
__device__ __forceinline__ unsigned short f2bf(float f) {
    unsigned u = __float_as_uint(f);
    unsigned rounding = 0x7FFFu + ((u >> 16) & 1u);
    return (unsigned short)((u + rounding) >> 16);
}

// ---------------- edge dtype detection ----------------
__global__ void detect_kernel(const void* edges, int E, int n_nodes, int* flag) {
    if (threadIdx.x == 0 && blockIdx.x == 0) {
        const long long* p = (const long long*)edges;
        int k = E < 64 ? E : 64;
        int is64 = 1;
        for (int i = 0; i < k; ++i) {
            long long v = p[i];
            if (v < 0 || v >= n_nodes) { is64 = 0; break; }
        }
        *flag = is64;
    }
}

__device__ __forceinline__ int load_edge(const void* edges, size_t idx, int is64) {
    return is64 ? (int)((const long long*)edges)[idx] : ((const int*)edges)[idx];
}

// ---------------- W -> Wt[col][k] bf16 (one-time, tiny) ----------------
__global__ void convert_wt(const float* __restrict__ W, unsigned short* __restrict__ Wt,
                           int K, int N) {
    int idx = blockIdx.x * 256 + threadIdx.x;
    if (idx >= K * N) return;
    int k = idx / N, n_ = idx % N;
    Wt[(size_t)n_ * K + k] = f2bf(W[idx]);
}

// ---------------- FUSED: x->bf16 convert || per-chunk LDS bucket histogram ----------------
// NO global atomics anywhere in the CSR build (fabric atomic ceiling, r8-r10).
// bucket = dst>>8 (391 buckets of 256 nodes). hist[bucket][chunk].
__global__ __launch_bounds__(1024) void conv_hist(
    const float* __restrict__ x, unsigned short* __restrict__ xb, int nconv,
    const void* edges, const int* __restrict__ flag,
    int* __restrict__ hist, int E, int NB, int CH, int CONV) {
    __shared__ int h[MAXNB];
    const int bid = blockIdx.x;
    if (bid < CONV) {
        int t = bid * 1024 + threadIdx.x;
        int stride = CONV * 1024;
        for (int i = t; i < nconv; i += stride) {
            const float4* p = (const float4*)(x + (size_t)i * 8);
            float4 a = p[0], b = p[1];
            union { unsigned short u[8]; uint4 v; } t8;
            t8.u[0] = f2bf(a.x); t8.u[1] = f2bf(a.y); t8.u[2] = f2bf(a.z); t8.u[3] = f2bf(a.w);
            t8.u[4] = f2bf(b.x); t8.u[5] = f2bf(b.y); t8.u[6] = f2bf(b.z); t8.u[7] = f2bf(b.w);
            *(uint4*)(xb + (size_t)i * 8) = t8.v;
        }
        return;
    }
    const int c = bid - CONV;
    for (int b = threadIdx.x; b < NB; b += 1024) h[b] = 0;
    __syncthreads();
    const int f = *flag;
    const int e0 = c * CHUNK + threadIdx.x;
    #pragma unroll
    for (int k = 0; k < CHUNK / 1024; ++k) {
        int e = e0 + k * 1024;
        if (e < E) {
            int d = load_edge(edges, (size_t)E + e, f);
            atomicAdd(&h[d >> 8], 1);                 // LDS atomic
        }
    }
    __syncthreads();
    for (int b = threadIdx.x; b < NB; b += 1024)
        hist[(size_t)b * CH + c] = h[b];
}

// ---------------- per-bucket exclusive scan over chunks (CH <= 512) ----------------
__global__ __launch_bounds__(512) void scan_chunks(
    int* __restrict__ hist, int* __restrict__ bucketTotal, int NB, int CH) {
    __shared__ int tmp[512];
    const int b = blockIdx.x;
    const int t = threadIdx.x;
    int v = (t < CH) ? hist[(size_t)b * CH + t] : 0;
    tmp[t] = v;
    __syncthreads();
    for (int off = 1; off < 512; off <<= 1) {
        int u = (t >= off) ? tmp[t - off] : 0;
        __syncthreads();
        if (t >= off) tmp[t] += u;
        __syncthreads();
    }
    if (t < CH) hist[(size_t)b * CH + t] = tmp[t] - v;   // exclusive over chunks
    if (t == 511) bucketTotal[b] = tmp[511];
}

// ---------------- exclusive scan over bucket totals (NB <= 512) ----------------
__global__ __launch_bounds__(512) void scan_buckets(int* __restrict__ base, int NB, int Etot) {
    __shared__ int tmp[512];
    const int t = threadIdx.x;
    int v = (t < NB) ? base[t] : 0;
    tmp[t] = v;
    __syncthreads();
    for (int off = 1; off < 512; off <<= 1) {
        int u = (t >= off) ? tmp[t - off] : 0;
        __syncthreads();
        if (t >= off) tmp[t] += u;
        __syncthreads();
    }
    if (t < NB) base[t] = tmp[t] - v;
    if (t == 0) base[NB] = Etot;
}

// ---------------- partition edges into dst-buckets (LDS cursors only) ----------------
// epart[pos] = src | dstlocal<<24  (src < 2^17, dstlocal < 256)
__global__ __launch_bounds__(1024) void partition_edges(
    const void* edges, const int* __restrict__ flag,
    const int* __restrict__ chunkBase, const int* __restrict__ bucketBase,
    unsigned* __restrict__ epart, int E, int NB, int CH) {
    __shared__ int cur[MAXNB];
    const int c = blockIdx.x;
    for (int b = threadIdx.x; b < NB; b += 1024)
        cur[b] = chunkBase[(size_t)b * CH + c] + bucketBase[b];
    __syncthreads();
    const int f = *flag;
    const int e0 = c * CHUNK + threadIdx.x;
    #pragma unroll
    for (int k = 0; k < CHUNK / 1024; ++k) {
        int e = e0 + k * 1024;
        if (e < E) {
            int d = load_edge(edges, (size_t)E + e, f);
            int s = load_edge(edges, e, f);
            int pos = atomicAdd(&cur[d >> 8], 1);     // LDS atomic (returning, fast)
            epart[pos] = (unsigned)s | ((unsigned)(d & 255) << 24);
        }
    }
}

// ---------------- per-bucket counting sort -> ssrc, deg, row_ptr, dis ----------------
__global__ __launch_bounds__(256) void bucket_sort(
    const unsigned* __restrict__ epart, const int* __restrict__ bucketBase,
    int* __restrict__ ssrc, int* __restrict__ deg, int* __restrict__ row_ptr,
    float* __restrict__ dis, int n) {
    __shared__ int cnt[256];
    __shared__ int tmp[256];
    __shared__ int cursor[256];
    const int b = blockIdx.x;
    const int t = threadIdx.x;
    const int bstart = bucketBase[b], bend = bucketBase[b + 1];
    cnt[t] = 0;
    __syncthreads();
    for (int i = bstart + t; i < bend; i += 256)
        atomicAdd(&cnt[epart[i] >> 24], 1);           // LDS atomic
    __syncthreads();
    int v = cnt[t];
    tmp[t] = v;
    __syncthreads();
    for (int off = 1; off < 256; off <<= 1) {
        int u = (t >= off) ? tmp[t - off] : 0;
        __syncthreads();
        if (t >= off) tmp[t] += u;
        __syncthreads();
    }
    int excl = tmp[t] - v;
    cursor[t] = excl;
    int node = b * 256 + t;
    if (node < n) {
        deg[node] = v;
        row_ptr[node] = bstart + excl;
        dis[node] = rsqrtf((float)v + 1.0f);          // +1 self-loop
    }
    __syncthreads();
    for (int i = bstart + t; i < bend; i += 256) {
        unsigned p = epart[i];
        int pos = bstart + atomicAdd(&cursor[p >> 24], 1);
        ssrc[pos] = (int)(p & 0xFFFFFFu);
    }
}

// ---------------- MFMA bf16 GEMM: C = bf16((A@Wt^T)*dis[row]) ----------------
// TM=64, KC=64, 256 thr (4 waves). LDS linear rows (128B) + T2 XOR-swizzle
// col16 ^= row&7 (conflict-free write+read). Fragments (r8/r9 HW-verified):
// A row=lane&15, k=ksub*32+8*(lane>>4)+j; B col=lane&15 same k;
// C/D col=lane&15, row=4*(lane>>4)+reg.
template<int TN, int K>
__global__ __launch_bounds__(256) void gemm_mfma_bb(
    const unsigned short* __restrict__ A, const unsigned short* __restrict__ Wt,
    const float* __restrict__ dis, unsigned short* __restrict__ C, int M) {
    constexpr int TM = 64, KC = 64, NCF = TN / 16;
    __shared__ __align__(16) unsigned short A_lds[TM * KC];
    __shared__ __align__(16) unsigned short B_lds[TN * KC];
    const int tid  = threadIdx.x;
    const int wave = tid >> 6;
    const int lane = tid & 63;
    const int q    = lane >> 4;
    const int cl   = lane & 15;
    const long long row0 = (long long)blockIdx.x * TM;

    f32x4 acc[NCF];
    const f32x4 fzero = {0.f, 0.f, 0.f, 0.f};
    #pragma unroll
    for (int cf = 0; cf < NCF; ++cf) acc[cf] = fzero;

    for (int k0 = 0; k0 < K; k0 += KC) {
        #pragma unroll
        for (int p = 0; p < 2; ++p) {
            int i = p * 256 + tid;
            int r = i >> 3, c = i & 7;
            uint4 v = *(const uint4*)(A + (row0 + r) * K + k0 + c * 8);
            *(uint4*)((char*)A_lds + r * 128 + ((c ^ (r & 7)) * 16)) = v;
        }
        #pragma unroll
        for (int p = 0; p < TN / 32; ++p) {
            int i = p * 256 + tid;
            int bc = i >> 3, c = i & 7;
            uint4 v = *(const uint4*)(Wt + (size_t)bc * K + k0 + c * 8);
            *(uint4*)((char*)B_lds + bc * 128 + ((c ^ (bc & 7)) * 16)) = v;
        }
        __syncthreads();
        #pragma unroll
        for (int ksub = 0; ksub < 2; ++ksub) {
            const int cidx = ksub * 4 + q;
            const int r = wave * 16 + cl;
            bf16x8 af = *(const bf16x8*)((const char*)A_lds + r * 128 + ((cidx ^ (r & 7)) * 16));
            #pragma unroll
            for (int cf = 0; cf < NCF; ++cf) {
                const int bc = cf * 16 + cl;
                bf16x8 bfr = *(const bf16x8*)((const char*)B_lds + bc * 128 + ((cidx ^ (bc & 7)) * 16));
                acc[cf] = __builtin_amdgcn_mfma_f32_16x16x32_bf16(af, bfr, acc[cf], 0, 0, 0);
            }
        }
        __syncthreads();
    }
    #pragma unroll
    for (int j = 0; j < 4; ++j) {
        long long row = row0 + wave * 16 + q * 4 + j;
        if (row >= M) continue;
        float d = dis[row];
        #pragma unroll
        for (int cf = 0; cf < NCF; ++cf)
            C[row * TN + cf * 16 + cl] = f2bf(acc[cf][j] * d);
    }
}

// ---------------- CSR gather on bf16 hs; output f32 or bf16; 8-deep MLP ----------------
template<int C, int NPB, bool OBF>
__global__ __launch_bounds__(256) void gather_layer_bf(
    const unsigned short* __restrict__ hs, const int* __restrict__ row_ptr,
    const int* __restrict__ deg, const int* __restrict__ ssrc,
    const float* __restrict__ dis, const float* __restrict__ bias,
    void* __restrict__ outp, int n) {
    constexpr int TPN = C / 8;
    const int local = threadIdx.x / TPN;
    const int lane  = threadIdx.x % TPN;
    const int i = blockIdx.x * NPB + local;
    if (i >= n) return;
    const uint4* h4 = (const uint4*)hs;
    float di = dis[i];
    float acc[8] = {};
    auto accum = [&](uint4 u) {
        acc[0] += __uint_as_float(u.x << 16);
        acc[1] += __uint_as_float(u.x & 0xffff0000u);
        acc[2] += __uint_as_float(u.y << 16);
        acc[3] += __uint_as_float(u.y & 0xffff0000u);
        acc[4] += __uint_as_float(u.z << 16);
        acc[5] += __uint_as_float(u.z & 0xffff0000u);
        acc[6] += __uint_as_float(u.w << 16);
        acc[7] += __uint_as_float(u.w & 0xffff0000u);
    };
    accum(h4[(size_t)i * TPN + lane]);     // self term
    const int start = row_ptr[i];
    const int cnt   = deg[i];
    const int* sp = ssrc + start;
    int j = 0;
    for (; j + 8 <= cnt; j += 8) {
        uint4 v[8];
        #pragma unroll
        for (int k = 0; k < 8; ++k) v[k] = h4[(size_t)sp[j + k] * TPN + lane];
        #pragma unroll
        for (int k = 0; k < 8; ++k) accum(v[k]);
    }
    for (; j + 4 <= cnt; j += 4) {
        uint4 v[4];
        #pragma unroll
        for (int k = 0; k < 4; ++k) v[k] = h4[(size_t)sp[j + k] * TPN + lane];
        #pragma unroll
        for (int k = 0; k < 4; ++k) accum(v[k]);
    }
    for (; j < cnt; ++j) accum(h4[(size_t)sp[j] * TPN + lane]);
    const float* bp = bias + lane * 8;
    float o[8];
    #pragma unroll
    for (int k = 0; k < 8; ++k) o[k] = bp[k] + di * acc[k];
    if constexpr (OBF) {
        union { unsigned short u[8]; uint4 v; } t8;
        #pragma unroll
        for (int k = 0; k < 8; ++k) t8.u[k] = f2bf(o[k]);
        *(uint4*)((unsigned short*)outp + (size_t)i * C + lane * 8) = t8.v;
    } else {
        float* op = (float*)outp + (size_t)i * C + lane * 8;
        *(float4*)op = make_float4(o[0], o[1], o[2], o[3]);
        *(float4*)(op + 4) = make_float4(o[4], o[5], o[6], o[7]);
    }
}

extern "C" void kernel_launch(void* const* d_in, const int* in_sizes, int n_in,
                              void* d_out, int out_size, void* d_ws, size_t ws_size,
                              hipStream_t stream) {
    const float* x     = (const float*)d_in[0];
    const void*  edges = d_in[1];
    const float* W1    = (const float*)d_in[2];
    const float* b1    = (const float*)d_in[3];
    const float* W2    = (const float*)d_in[4];
    const float* b2    = (const float*)d_in[5];
    float* out = (float*)d_out;

    const int n  = in_sizes[0] / IN_C;         // 100000
    const int E  = in_sizes[1] / 2;            // 1600000
    const int NB = (n + 255) / 256;            // 391 buckets
    const int CH = (E + CHUNK - 1) / CHUNK;    // 391 chunks (<=512)

    // ---- workspace carve-up (256B-aligned), ~118 MB ----
    char* ws = (char*)d_ws;
    size_t off = 0;
    auto alloc = [&](size_t bytes) { char* p = ws + off; off += (bytes + 255) & ~(size_t)255; return p; };
    int*   flag       = (int*)  alloc(4);
    int*   hist       = (int*)  alloc((size_t)NB * CH * 4);   // chunk-excl after scan
    int*   bucketBase = (int*)  alloc((size_t)(NB + 1) * 4);
    int*   deg        = (int*)  alloc((size_t)n * 4);
    int*   row_ptr    = (int*)  alloc((size_t)n * 4);
    float* dis        = (float*)alloc((size_t)n * 4);
    unsigned* epart   = (unsigned*)alloc((size_t)E * 4);
    int*   ssrc       = (int*)  alloc((size_t)E * 4);
    unsigned short* xb   = (unsigned short*)alloc((size_t)(n + 64) * IN_C * 2);
    unsigned short* hs   = (unsigned short*)alloc((size_t)(n + 64) * HID_C * 2);
    unsigned short* aggb = (unsigned short*)alloc((size_t)(n + 64) * HID_C * 2);
    unsigned short* Wt1  = (unsigned short*)alloc((size_t)IN_C * HID_C * 2);
    unsigned short* Wt2  = (unsigned short*)alloc((size_t)HID_C * OUT_C * 2);

    // 1. detect + weight transpose/convert
    detect_kernel<<<1, 64, 0, stream>>>(edges, E, n, flag);
    convert_wt<<<(IN_C * HID_C + 255) / 256, 256, 0, stream>>>(W1, Wt1, IN_C, HID_C);
    convert_wt<<<(HID_C * OUT_C + 255) / 256, 256, 0, stream>>>(W2, Wt2, HID_C, OUT_C);

    // 2. FUSED: x->bf16 || per-chunk bucket histogram (zero global atomics)
    const int CONV = 256;
    const int nconv = n * IN_C / 8;
    conv_hist<<<CONV + CH, 1024, 0, stream>>>(x, xb, nconv, edges, flag, hist, E, NB, CH, CONV);

    // 3. scans: per-bucket over chunks, then over buckets
    scan_chunks<<<NB, 512, 0, stream>>>(hist, bucketBase, NB, CH);
    scan_buckets<<<1, 512, 0, stream>>>(bucketBase, NB, E);

    // 4. partition into dst-buckets (LDS cursors), then per-bucket counting sort
    partition_edges<<<CH, 1024, 0, stream>>>(edges, flag, hist, bucketBase, epart, E, NB, CH);
    bucket_sort<<<NB, 256, 0, stream>>>(epart, bucketBase, ssrc, deg, row_ptr, dis, n);

    // 5. layer 1: hs = bf16((xb@W1)*dis); aggb = bf16(b1 + dis*(self+gather))
    gemm_mfma_bb<HID_C, IN_C><<<(n + 63) / 64, 256, 0, stream>>>(xb, Wt1, dis, hs, n);
    gather_layer_bf<HID_C, 16, true><<<(n + 15) / 16, 256, 0, stream>>>(hs, row_ptr, deg, ssrc, dis, b1, aggb, n);

    // 6. layer 2: hs2 = bf16((aggb@W2)*dis); out = b2 + dis*(self+gather)
    gemm_mfma_bb<OUT_C, HID_C><<<(n + 63) / 64, 256, 0, stream>>>(aggb, Wt2, dis, hs, n);
    gather_layer_bf<OUT_C, 32, false><<<(n + 31) / 32, 256, 0, stream>>>(hs, row_ptr, deg, ssrc, dis, b2, out, n);
}